// Round 1
// baseline (26211.801 us; speedup 1.0000x reference)
//
#include <hip/hip_runtime.h>
#include <cmath>

// ---------------- constants ----------------
namespace {
constexpr int BSZ = 2;
constexpr int IMGSZ = 512;
constexpr int GRIDP = 32;          // 512/16
constexpr int NPATCHES = 1024;
constexpr int CH = 768;
constexpr int LAYERS = 12;
constexpr int NHEADS = 12;
constexpr int DHEAD = 64;
constexpr int NQUERY = 100;
constexpr int NPREFIX = 5;
constexpr int NCLASS = 151;        // NCLS+1
constexpr int NBLK = 4;
constexpr int NTOK1 = NPREFIX + NPATCHES;          // 1029
constexpr int NTOK2 = NQUERY + NPREFIX + NPATCHES; // 1129
constexpr int QT = 8;              // query rows per attention workgroup
}

__device__ __forceinline__ float geluf(float v) {
  return 0.5f * v * (1.0f + erff(v * 0.70710678118654752f));
}

// ---------------- patchify + normalize ----------------
// XP[(b*1024+p)][c*256+py*16+px] = (x[b,c,gy*16+py,gx*16+px]/255 - mean[c]) / std[c]
__global__ void k_patchify(const float* __restrict__ x, const float* __restrict__ mean,
                           const float* __restrict__ stdv, float* __restrict__ xp) {
  int idx = blockIdx.x * 256 + threadIdx.x;
  if (idx >= BSZ * NPATCHES * CH) return;
  int f = idx % CH;
  int p = (idx / CH) % NPATCHES;
  int b = idx / (CH * NPATCHES);
  int c = f >> 8;               // /256
  int py = (f >> 4) & 15;
  int px = f & 15;
  int gy = p >> 5, gx = p & 31;
  float v = x[((size_t)(b * 3 + c) * IMGSZ + gy * 16 + py) * IMGSZ + gx * 16 + px];
  xp[idx] = (v * (1.0f / 255.0f) - mean[c]) / stdv[c];
}

// ---------------- generic tiled fp32 GEMM ----------------
// BMODE 0: C[m,n] = sum_k A[m,k] * B[n,k]   (B is weight (N,K))
// BMODE 1: C[m,n] = sum_k A[m,k] * B[k,n]
// epilogue: optional bias[n], optional exact gelu, optional upsample scatter:
//   wmap=W>0: store at C[m*ldc + (n/W)*4W + (n%W)*2]  (caller adds d*2W+x to C base)
// Requirements: K % 16 == 0; lda,ldb % 4 == 0; for BMODE1 N % 64 == 0.
template <int BMODE>
__global__ __launch_bounds__(256) void k_gemm(const float* __restrict__ A,
                                              const float* __restrict__ B,
                                              float* __restrict__ C,
                                              const float* __restrict__ bias,
                                              int M, int N, int K, int lda, int ldb, int ldc,
                                              int dogelu, int wmap) {
  __shared__ float As[64][20];   // [m][k], padded row=20 floats (80B, 16B aligned)
  __shared__ float Bs[16][68];   // [k][n], padded row=68 floats (272B, 16B aligned)
  const int tid = threadIdx.x;
  const int m0 = blockIdx.y * 64, n0 = blockIdx.x * 64;
  const int tx = tid & 15, ty = tid >> 4;
  const int ar = tid >> 2, ac = (tid & 3) << 2;
  float acc[4][4] = {};
  for (int k0 = 0; k0 < K; k0 += 16) {
    float4 av = make_float4(0.f, 0.f, 0.f, 0.f);
    if (m0 + ar < M) av = *(const float4*)(A + (size_t)(m0 + ar) * lda + k0 + ac);
    *(float4*)&As[ar][ac] = av;
    if (BMODE == 0) {
      float4 bv = make_float4(0.f, 0.f, 0.f, 0.f);
      if (n0 + ar < N) bv = *(const float4*)(B + (size_t)(n0 + ar) * ldb + k0 + ac);
      Bs[ac + 0][ar] = bv.x; Bs[ac + 1][ar] = bv.y;
      Bs[ac + 2][ar] = bv.z; Bs[ac + 3][ar] = bv.w;
    } else {
      const int kk = tid >> 4, cc = (tid & 15) << 2;
      float4 bv = *(const float4*)(B + (size_t)(k0 + kk) * ldb + n0 + cc);
      *(float4*)&Bs[kk][cc] = bv;
    }
    __syncthreads();
#pragma unroll
    for (int k = 0; k < 16; k += 4) {
      float b4[4][4];
#pragma unroll
      for (int kk = 0; kk < 4; kk++) {
        float4 t = *(const float4*)&Bs[k + kk][tx << 2];
        b4[kk][0] = t.x; b4[kk][1] = t.y; b4[kk][2] = t.z; b4[kk][3] = t.w;
      }
#pragma unroll
      for (int i = 0; i < 4; i++) {
        float4 t = *(const float4*)&As[(ty << 2) + i][k];
        float a4[4] = {t.x, t.y, t.z, t.w};
#pragma unroll
        for (int kk = 0; kk < 4; kk++)
#pragma unroll
          for (int j = 0; j < 4; j++) acc[i][j] = fmaf(a4[kk], b4[kk][j], acc[i][j]);
      }
    }
    __syncthreads();
  }
#pragma unroll
  for (int i = 0; i < 4; i++) {
    int m = m0 + (ty << 2) + i;
    if (m >= M) break;
#pragma unroll
    for (int j = 0; j < 4; j++) {
      int n = n0 + (tx << 2) + j;
      if (n >= N) continue;
      float v = acc[i][j];
      if (bias) v += bias[n];
      if (dogelu) v = geluf(v);
      size_t off;
      if (wmap) off = (size_t)m * ldc + (size_t)(n / wmap) * (4 * wmap) + (n % wmap) * 2;
      else      off = (size_t)m * ldc + n;
      C[off] = v;
    }
  }
}

// ---------------- token LayerNorm (row of 768) ----------------
__global__ __launch_bounds__(256) void k_ln(const float* __restrict__ X,
                                            const float* __restrict__ w,
                                            const float* __restrict__ b,
                                            float* __restrict__ out) {
  const int row = blockIdx.x, tid = threadIdx.x;
  const float* xr = X + (size_t)row * CH;
  float v0 = xr[tid], v1 = xr[tid + 256], v2 = xr[tid + 512];
  __shared__ float red[256];
  red[tid] = v0 + v1 + v2;
  __syncthreads();
  for (int s = 128; s > 0; s >>= 1) { if (tid < s) red[tid] += red[tid + s]; __syncthreads(); }
  float m = red[0] * (1.0f / CH);
  __syncthreads();
  float d0 = v0 - m, d1 = v1 - m, d2 = v2 - m;
  red[tid] = d0 * d0 + d1 * d1 + d2 * d2;
  __syncthreads();
  for (int s = 128; s > 0; s >>= 1) { if (tid < s) red[tid] += red[tid + s]; __syncthreads(); }
  float rstd = rsqrtf(red[0] * (1.0f / CH) + 1e-6f);
  float* orow = out + (size_t)row * CH;
  orow[tid]       = d0 * rstd * w[tid]       + b[tid];
  orow[tid + 256] = d1 * rstd * w[tid + 256] + b[tid + 256];
  orow[tid + 512] = d2 * rstd * w[tid + 512] + b[tid + 512];
}

// ---------------- fused attention ----------------
// one workgroup per (b, head, 8 query rows); qkv row: [q(768)|k(768)|v(768)]
__global__ __launch_bounds__(256) void k_attn(const float* __restrict__ qkv,
                                              float* __restrict__ out,
                                              const unsigned char* __restrict__ qm,
                                              int Ntok) {
  const int b = blockIdx.z, h = blockIdx.y, q0 = blockIdx.x * QT;
  const int tid = threadIdx.x;
  __shared__ float qs[QT][DHEAD];
  __shared__ float ks[64][DHEAD + 1];
  __shared__ float srow[QT][1152];
  __shared__ float red[256];
  __shared__ float inv[QT];

  for (int idx = tid; idx < QT * DHEAD; idx += 256) {
    int r = idx >> 6, d = idx & 63;
    float v = 0.f;
    if (q0 + r < Ntok) v = qkv[(size_t)(b * Ntok + q0 + r) * (3 * CH) + h * DHEAD + d] * 0.125f;
    qs[r][d] = v;
  }
  __syncthreads();

  const int kj = tid >> 2, kd0 = (tid & 3) << 4;
  const int jj = tid & 63, rg = tid >> 6;
  for (int nb = 0; nb < Ntok; nb += 64) {
    const int nk = min(64, Ntok - nb);
    if (kj < nk) {
      const float* kp = qkv + (size_t)(b * Ntok + nb + kj) * (3 * CH) + CH + h * DHEAD + kd0;
#pragma unroll
      for (int i = 0; i < 16; i++) ks[kj][kd0 + i] = kp[i];
    }
    __syncthreads();
    if (jj < nk) {
      float a0 = 0.f, a1 = 0.f;
#pragma unroll 8
      for (int d = 0; d < DHEAD; d++) {
        float kv = ks[jj][d];
        a0 = fmaf(qs[rg][d], kv, a0);
        a1 = fmaf(qs[rg + 4][d], kv, a1);
      }
      int n = nb + jj;
      if (qm && n >= NQUERY + NPREFIX) {
        int r0 = q0 + rg, r1 = q0 + rg + 4;
        int pk = n - (NQUERY + NPREFIX);
        if (r0 < NQUERY && !qm[(b * NQUERY + r0) * NPATCHES + pk]) a0 = -1e30f;
        if (r1 < NQUERY && !qm[(b * NQUERY + r1) * NPATCHES + pk]) a1 = -1e30f;
      }
      srow[rg][n] = a0;
      srow[rg + 4][n] = a1;
    }
    __syncthreads();
  }

  for (int r = 0; r < QT; r++) {
    float mx = -1e30f;
    for (int n = tid; n < Ntok; n += 256) mx = fmaxf(mx, srow[r][n]);
    red[tid] = mx; __syncthreads();
    for (int s = 128; s > 0; s >>= 1) { if (tid < s) red[tid] = fmaxf(red[tid], red[tid + s]); __syncthreads(); }
    mx = red[0]; __syncthreads();
    float sum = 0.f;
    for (int n = tid; n < Ntok; n += 256) {
      float e = __expf(srow[r][n] - mx);
      srow[r][n] = e; sum += e;
    }
    red[tid] = sum; __syncthreads();
    for (int s = 128; s > 0; s >>= 1) { if (tid < s) red[tid] += red[tid + s]; __syncthreads(); }
    if (tid == 0) inv[r] = 1.0f / red[0];
    __syncthreads();
  }

  const int d = tid & 63, qr = tid >> 6;
  float oacc[QT];
#pragma unroll
  for (int r = 0; r < QT; r++) oacc[r] = 0.f;
  for (int n = qr; n < Ntok; n += 4) {
    float vv = qkv[(size_t)(b * Ntok + n) * (3 * CH) + 2 * CH + h * DHEAD + d];
#pragma unroll
    for (int r = 0; r < QT; r++) oacc[r] = fmaf(srow[r][n], vv, oacc[r]);
  }
  for (int r = 0; r < QT; r++) {
    red[tid] = oacc[r]; __syncthreads();
    if (qr == 0 && q0 + r < Ntok) {
      float t = (red[d] + red[64 + d]) + (red[128 + d] + red[192 + d]);
      out[(size_t)(b * Ntok + q0 + r) * CH + h * DHEAD + d] = t * inv[r];
    }
    __syncthreads();
  }
}

// ---------------- small elementwise kernels ----------------
__global__ void k_assemble(const float* __restrict__ xpe, const float* __restrict__ prefix,
                           const float* __restrict__ pos, float* __restrict__ X) {
  int idx = blockIdx.x * 256 + threadIdx.x;
  if (idx >= BSZ * NTOK1 * CH) return;
  int c = idx % CH;
  int n = (idx / CH) % NTOK1;
  int b = idx / (CH * NTOK1);
  float v;
  if (n < NPREFIX) v = prefix[n * CH + c];
  else v = xpe[((size_t)b * NPATCHES + n - NPREFIX) * CH + c] + pos[(size_t)(n - NPREFIX) * CH + c];
  X[idx] = v;
}

__global__ void k_concat(const float* __restrict__ Xin, const float* __restrict__ qe,
                         float* __restrict__ Xout) {
  int idx = blockIdx.x * 256 + threadIdx.x;
  if (idx >= BSZ * NTOK2 * CH) return;
  int c = idx % CH;
  int n = (idx / CH) % NTOK2;
  int b = idx / (CH * NTOK2);
  float v;
  if (n < NQUERY) v = qe[n * CH + c];
  else v = Xin[((size_t)b * NTOK1 + n - NQUERY) * CH + c];
  Xout[idx] = v;
}

__global__ void k_residual(float* __restrict__ X, const float* __restrict__ Y,
                           const float* __restrict__ ls, int total) {
  int idx = blockIdx.x * 256 + threadIdx.x;
  if (idx >= total) return;
  X[idx] += ls[idx % CH] * Y[idx];
}

__global__ void k_biasgelu(float* __restrict__ F, const float* __restrict__ bias, int HW) {
  int idx = blockIdx.x * 256 + threadIdx.x;
  if (idx >= CH * HW) return;
  int c = idx / HW;
  F[idx] = geluf(F[idx] + bias[c]);
}

__global__ void k_dwconv(const float* __restrict__ in, const float* __restrict__ w9,
                         float* __restrict__ out, int H, int W) {
  int idx = blockIdx.x * 256 + threadIdx.x;
  if (idx >= CH * H * W) return;
  int x = idx % W;
  int y = (idx / W) % H;
  int c = idx / (W * H);
  const float* wp = w9 + c * 9;
  const float* ip = in + (size_t)c * H * W;
  float s = 0.f;
#pragma unroll
  for (int ky = 0; ky < 3; ky++) {
    int yy = y + ky - 1;
    if (yy < 0 || yy >= H) continue;
#pragma unroll
    for (int kx = 0; kx < 3; kx++) {
      int xx = x + kx - 1;
      if (xx < 0 || xx >= W) continue;
      s = fmaf(wp[ky * 3 + kx], ip[(size_t)yy * W + xx], s);
    }
  }
  out[idx] = s;
}

// channel LayerNorm on (C,H,W): normalize over C at each pixel; 64 pixels per block
__global__ __launch_bounds__(256) void k_lnc(float* __restrict__ F, const float* __restrict__ w,
                                             const float* __restrict__ b, int HW) {
  int p0 = blockIdx.x * 64;
  int tid = threadIdx.x;
  int p = tid & 63, cg = tid >> 6;
  float s = 0.f, ss = 0.f;
  for (int c = cg; c < CH; c += 4) {
    float v = F[(size_t)c * HW + p0 + p];
    s += v; ss = fmaf(v, v, ss);
  }
  __shared__ float S[4][64], SS[4][64], MEAN[64], RSTD[64];
  S[cg][p] = s; SS[cg][p] = ss;
  __syncthreads();
  if (cg == 0) {
    float t = S[0][p] + S[1][p] + S[2][p] + S[3][p];
    float t2 = SS[0][p] + SS[1][p] + SS[2][p] + SS[3][p];
    float m = t * (1.0f / CH);
    float var = fmaxf(t2 * (1.0f / CH) - m * m, 0.f);
    MEAN[p] = m; RSTD[p] = rsqrtf(var + 1e-6f);
  }
  __syncthreads();
  for (int c = cg; c < CH; c += 4) {
    size_t off = (size_t)c * HW + p0 + p;
    F[off] = (F[off] - MEAN[p]) * RSTD[p] * w[c] + b[c];
  }
}

// transpose (1024 patches, 768 ch) -> (768, 1024)
__global__ __launch_bounds__(256) void k_transpose(const float* __restrict__ in,
                                                   float* __restrict__ F0) {
  __shared__ float t[32][33];
  int bx = blockIdx.x * 32;  // patch
  int by = blockIdx.y * 32;  // channel
  int x = threadIdx.x & 31, y = threadIdx.x >> 5;
#pragma unroll
  for (int i = 0; i < 4; i++) t[y + i * 8][x] = in[(size_t)(bx + y + i * 8) * CH + by + x];
  __syncthreads();
#pragma unroll
  for (int i = 0; i < 4; i++)
    F0[(size_t)(by + y + i * 8) * NPATCHES + bx + x] = t[x][y + i * 8];
}

// repack upt_w (s, c, o, d, x) -> WP[s][dx][o][c]
__global__ __launch_bounds__(256) void k_repack(const float* __restrict__ upt,
                                                float* __restrict__ WP) {
  __shared__ float t[4][32][33];
  int o0 = blockIdx.x * 32, c0 = blockIdx.y * 32, s = blockIdx.z;
  int tid = threadIdx.x;
  for (int idx = tid; idx < 32 * 128; idx += 256) {
    int cc = idx >> 7;
    int rest = idx & 127;
    int oo = rest >> 2, dx = rest & 3;
    t[dx][oo][cc] = upt[((size_t)(s * CH + c0 + cc) * CH + o0 + oo) * 4 + dx];
  }
  __syncthreads();
  for (int idx = tid; idx < 4 * 32 * 32; idx += 256) {
    int dx = idx >> 10;
    int oo = (idx >> 5) & 31;
    int cc = idx & 31;
    WP[((size_t)(s * 4 + dx) * CH + o0 + oo) * CH + c0 + cc] = t[dx][oo][cc];
  }
}

// antialiased bilinear 128->32 downsample + threshold>0 (jax.image.resize semantics)
__global__ void k_qmask(const float* __restrict__ mlog, unsigned char* __restrict__ qm) {
  int idx = blockIdx.x * 256 + threadIdx.x;
  if (idx >= BSZ * NQUERY * NPATCHES) return;
  int gx = idx & 31;
  int gy = (idx >> 5) & 31;
  int bq = idx >> 10;
  const float* m = mlog + (size_t)bq * 16384;
  float cy = 4.0f * gy + 1.5f, cx = 4.0f * gx + 1.5f;
  int y0 = max(0, 4 * gy - 2), y1 = min(127, 4 * gy + 5);
  int x0 = max(0, 4 * gx - 2), x1 = min(127, 4 * gx + 5);
  float num = 0.f;
  for (int jy = y0; jy <= y1; jy++) {
    float wy = 1.0f - fabsf((float)jy - cy) * 0.25f;
    float rowsum = 0.f;
    for (int jx = x0; jx <= x1; jx++) {
      float wx = 1.0f - fabsf((float)jx - cx) * 0.25f;
      rowsum = fmaf(wx, m[jy * 128 + jx], rowsum);
    }
    num = fmaf(wy, rowsum, num);
  }
  // per-dim normalizers are positive -> sign(num) == sign(normalized value)
  qm[idx] = (num > 0.0f) ? 1 : 0;
}

// ---------------- host orchestration ----------------
extern "C" void kernel_launch(void* const* d_in, const int* in_sizes, int n_in,
                              void* d_out_v, int out_size, void* d_ws, size_t ws_size,
                              hipStream_t stream) {
  (void)in_sizes; (void)n_in; (void)out_size; (void)ws_size;
  const float* x_in    = (const float*)d_in[0];
  const float* pmean   = (const float*)d_in[1];
  const float* pstd    = (const float*)d_in[2];
  const float* patch_w = (const float*)d_in[3];
  const float* patch_b = (const float*)d_in[4];
  const float* pos     = (const float*)d_in[5];
  const float* prefix  = (const float*)d_in[6];
  const float* qkv_w   = (const float*)d_in[7];
  const float* qkv_b   = (const float*)d_in[8];
  const float* proj_w  = (const float*)d_in[9];
  const float* proj_b  = (const float*)d_in[10];
  const float* ln1w    = (const float*)d_in[11];
  const float* ln1b    = (const float*)d_in[12];
  const float* ln2w    = (const float*)d_in[13];
  const float* ln2b    = (const float*)d_in[14];
  const float* ls1     = (const float*)d_in[15];
  const float* ls2     = (const float*)d_in[16];
  const float* fc1w    = (const float*)d_in[17];
  const float* fc1b    = (const float*)d_in[18];
  const float* fc2w    = (const float*)d_in[19];
  const float* fc2b    = (const float*)d_in[20];
  const float* normw   = (const float*)d_in[21];
  const float* normb   = (const float*)d_in[22];
  const float* qemb    = (const float*)d_in[23];
  const float* clsw    = (const float*)d_in[24];
  const float* clsb    = (const float*)d_in[25];
  const float* mh1w    = (const float*)d_in[26];
  const float* mh1b    = (const float*)d_in[27];
  const float* mh2w    = (const float*)d_in[28];
  const float* mh2b    = (const float*)d_in[29];
  const float* mh3w    = (const float*)d_in[30];
  const float* mh3b    = (const float*)d_in[31];
  const float* uptw    = (const float*)d_in[32];
  const float* uptb    = (const float*)d_in[33];
  const float* updww   = (const float*)d_in[34];
  const float* uplnw   = (const float*)d_in[35];
  const float* uplnb   = (const float*)d_in[36];

  float* out = (float*)d_out_v;
  float* out_mask = out;                                        // (5,2,100,128,128)
  float* out_cls = out + (size_t)5 * BSZ * NQUERY * 16384;      // (5,2,100,151)

  float* w = (float*)d_ws;
  size_t off = 0;
  auto alloc = [&](size_t n) { float* p = w + off; off += (n + 3) & ~(size_t)3; return p; };
  float* XP   = alloc((size_t)BSZ * NPATCHES * CH);
  float* XPE  = alloc((size_t)BSZ * NPATCHES * CH);
  float* Xa   = alloc((size_t)BSZ * NTOK2 * CH);
  float* Xb   = alloc((size_t)BSZ * NTOK2 * CH);
  float* Hbuf = alloc((size_t)BSZ * NTOK2 * CH);
  float* H2   = alloc((size_t)BSZ * NTOK2 * CH);
  // shared region: {QKV,M1} live only during layer compute; {FA,FB} only during predict
  float* R    = alloc((size_t)2 * CH * 128 * 128);              // 25,165,824 floats
  float* QKV  = R;                                              // 2*1129*2304 = 5,202,432
  float* M1   = R + (size_t)BSZ * NTOK2 * 3 * CH;               // 2*1129*3072 = 6,936,576
  float* FA   = R;
  float* FB   = R + (size_t)CH * 128 * 128;
  float* HQ   = alloc((size_t)BSZ * NQUERY * CH);
  float* HQ2  = alloc((size_t)BSZ * NQUERY * CH);
  float* F0   = alloc((size_t)CH * NPATCHES);
  float* WP   = alloc((size_t)2 * 4 * CH * CH);
  unsigned char* QM = (unsigned char*)(w + off);
  off += (size_t)BSZ * NQUERY * NPATCHES / 4 + 4;

  auto gemm0 = [&](const float* A, const float* Bm, float* Cm, const float* bias,
                   int M, int N, int K, int lda, int ldb, int ldc, int dogelu) {
    dim3 g((N + 63) / 64, (M + 63) / 64);
    k_gemm<0><<<g, 256, 0, stream>>>(A, Bm, Cm, bias, M, N, K, lda, ldb, ldc, dogelu, 0);
  };
  auto gemm1 = [&](const float* A, const float* Bm, float* Cm,
                   int M, int N, int K, int lda, int ldb, int ldc, int wmap) {
    dim3 g((N + 63) / 64, (M + 63) / 64);
    k_gemm<1><<<g, 256, 0, stream>>>(A, Bm, Cm, nullptr, M, N, K, lda, ldb, ldc, 0, wmap);
  };
  auto ew = [&](int tot) { return dim3((tot + 255) / 256); };

  // ---- patch embedding ----
  k_patchify<<<ew(BSZ * NPATCHES * CH), 256, 0, stream>>>(x_in, pmean, pstd, XP);
  gemm0(XP, patch_w, XPE, patch_b, BSZ * NPATCHES, CH, CH, CH, CH, CH, 0);
  k_assemble<<<ew(BSZ * NTOK1 * CH), 256, 0, stream>>>(XPE, prefix, pos, Xa);

  float* X = Xa;
  float* Xalt = Xb;

  auto predict = [&](float* Xcur, int pred, bool build_mask) {
    k_ln<<<dim3(BSZ * NTOK2), 256, 0, stream>>>(Xcur, normw, normb, Hbuf);
    for (int b = 0; b < BSZ; b++) {
      const float* q = Hbuf + (size_t)b * NTOK2 * CH;
      gemm0(q, clsw, out_cls + (size_t)(pred * BSZ + b) * NQUERY * NCLASS, clsb,
            NQUERY, NCLASS, CH, CH, CH, NCLASS, 0);
      gemm0(q, mh1w, HQ + (size_t)b * NQUERY * CH, mh1b, NQUERY, CH, CH, CH, CH, CH, 1);
      gemm0(HQ + (size_t)b * NQUERY * CH, mh2w, HQ2 + (size_t)b * NQUERY * CH, mh2b,
            NQUERY, CH, CH, CH, CH, CH, 1);
      gemm0(HQ2 + (size_t)b * NQUERY * CH, mh3w, HQ + (size_t)b * NQUERY * CH, mh3b,
            NQUERY, CH, CH, CH, CH, CH, 0);
    }
    k_repack<<<dim3(24, 24, 2), 256, 0, stream>>>(uptw, WP);
    for (int b = 0; b < BSZ; b++) {
      k_transpose<<<dim3(32, 24), 256, 0, stream>>>(
          Hbuf + (size_t)(b * NTOK2 + NQUERY + NPREFIX) * CH, F0);
      // stage 0: F0 (768,32x32) -> FB (768,64x64)
      for (int dx = 0; dx < 4; dx++) {
        int d = dx >> 1, xo = dx & 1;
        gemm1(WP + (size_t)dx * CH * CH, F0, FB + d * 64 + xo,
              CH, 1024, CH, CH, 1024, 4096, 32);
      }
      k_biasgelu<<<ew(CH * 4096), 256, 0, stream>>>(FB, uptb, 4096);
      k_dwconv<<<ew(CH * 4096), 256, 0, stream>>>(FB, updww, FA, 64, 64);
      k_lnc<<<dim3(4096 / 64), 256, 0, stream>>>(FA, uplnw, uplnb, 4096);
      // stage 1: FA (768,64x64) -> FB (768,128x128)
      for (int dx = 0; dx < 4; dx++) {
        int d = dx >> 1, xo = dx & 1;
        gemm1(WP + (size_t)(4 + dx) * CH * CH, FA, FB + d * 128 + xo,
              CH, 4096, CH, CH, 4096, 16384, 64);
      }
      k_biasgelu<<<ew(CH * 16384), 256, 0, stream>>>(FB, uptb + CH, 16384);
      k_dwconv<<<ew(CH * 16384), 256, 0, stream>>>(FB, updww + CH * 9, FA, 128, 128);
      k_lnc<<<dim3(16384 / 64), 256, 0, stream>>>(FA, uplnw + CH, uplnb + CH, 16384);
      // mask logits: h (100,768) @ f (768,16384)
      gemm1(HQ + (size_t)b * NQUERY * CH, FA,
            out_mask + (size_t)(pred * BSZ + b) * NQUERY * 16384,
            NQUERY, 16384, CH, CH, 16384, 16384, 0);
    }
    if (build_mask) {
      k_qmask<<<ew(BSZ * NQUERY * NPATCHES), 256, 0, stream>>>(
          out_mask + (size_t)pred * BSZ * NQUERY * 16384, QM);
    }
  };

  int Ntok = NTOK1;
  for (int i = 0; i < LAYERS; i++) {
    if (i == LAYERS - NBLK) {
      k_concat<<<ew(BSZ * NTOK2 * CH), 256, 0, stream>>>(X, qemb, Xalt);
      float* t = X; X = Xalt; Xalt = t;
      Ntok = NTOK2;
    }
    if (i >= LAYERS - NBLK) predict(X, i - (LAYERS - NBLK), true);
    const int rows = BSZ * Ntok;
    // attention block
    k_ln<<<dim3(rows), 256, 0, stream>>>(X, ln1w + i * CH, ln1b + i * CH, Hbuf);
    gemm0(Hbuf, qkv_w + (size_t)i * 3 * CH * CH, QKV, qkv_b + (size_t)i * 3 * CH,
          rows, 3 * CH, CH, CH, CH, 3 * CH, 0);
    k_attn<<<dim3((Ntok + QT - 1) / QT, NHEADS, BSZ), 256, 0, stream>>>(
        QKV, H2, (i >= LAYERS - NBLK) ? QM : (const unsigned char*)nullptr, Ntok);
    gemm0(H2, proj_w + (size_t)i * CH * CH, Hbuf, proj_b + (size_t)i * CH,
          rows, CH, CH, CH, CH, CH, 0);
    k_residual<<<ew(rows * CH), 256, 0, stream>>>(X, Hbuf, ls1 + i * CH, rows * CH);
    // MLP block
    k_ln<<<dim3(rows), 256, 0, stream>>>(X, ln2w + i * CH, ln2b + i * CH, Hbuf);
    gemm0(Hbuf, fc1w + (size_t)i * 4 * CH * CH, M1, fc1b + (size_t)i * 4 * CH,
          rows, 4 * CH, CH, CH, CH, 4 * CH, 1);
    gemm0(M1, fc2w + (size_t)i * CH * 4 * CH, H2, fc2b + (size_t)i * CH,
          rows, CH, 4 * CH, 4 * CH, 4 * CH, CH, 0);
    k_residual<<<ew(rows * CH), 256, 0, stream>>>(X, H2, ls2 + i * CH, rows * CH);
  }
  predict(X, 4, false);
}

// Round 2
// 16012.405 us; speedup vs baseline: 1.6370x; 1.6370x over previous
//
#include <hip/hip_runtime.h>
#include <cmath>

// ---------------- constants ----------------
namespace {
constexpr int BSZ = 2;
constexpr int IMGSZ = 512;
constexpr int NPATCHES = 1024;
constexpr int CH = 768;
constexpr int LAYERS = 12;
constexpr int DHEAD = 64;
constexpr int NQUERY = 100;
constexpr int NPREFIX = 5;
constexpr int NCLASS = 151;
constexpr int NBLK = 4;
constexpr int NTOK1 = NPREFIX + NPATCHES;          // 1029
constexpr int NTOK2 = NQUERY + NPREFIX + NPATCHES; // 1129
constexpr int QT = 8;
}

typedef unsigned short u16;
typedef __bf16 bf16x8 __attribute__((ext_vector_type(8)));
typedef float floatx4 __attribute__((ext_vector_type(4)));

__device__ __forceinline__ float geluf(float v) {
  return 0.5f * v * (1.0f + erff(v * 0.70710678118654752f));
}
__device__ __forceinline__ u16 f2b(float f) {
  unsigned u = __float_as_uint(f);
  u += 0x7fffu + ((u >> 16) & 1u);
  return (u16)(u >> 16);
}
__device__ __forceinline__ float b2f(u16 v) {
  return __uint_as_float(((unsigned)v) << 16);
}
__device__ __forceinline__ void gl_lds16(const u16* g, u16* l) {
  __builtin_amdgcn_global_load_lds((const __attribute__((address_space(1))) void*)g,
                                   (__attribute__((address_space(3))) void*)l, 16, 0, 0);
}
__device__ __forceinline__ float ldv(const float* p) { return *p; }
__device__ __forceinline__ float ldv(const u16* p) { return b2f(*p); }

// ---------------- fp32 -> bf16 convert (n % 4 == 0) ----------------
__global__ void k_cvt(const float* __restrict__ s, u16* __restrict__ d, int n) {
  int i = (blockIdx.x * 256 + threadIdx.x) * 4;
  if (i >= n) return;
  float4 v = *(const float4*)(s + i);
  u16 r[4] = {f2b(v.x), f2b(v.y), f2b(v.z), f2b(v.w)};
  *(uint2*)(d + i) = *(const uint2*)r;
}

// ---------------- bf16 MFMA GEMM (m97 structure) ----------------
// C[m,n] = sum_k A[m,k] * B[n,k];  A: M x K (lda), B: N x K (ldb), both bf16
// 128x128 tile, BK=32, 256 thr = 4 waves (2x2 of 64x64), 16x16x32 mfma.
// flags: 1 = gelu; 2 = upsample scatter (gelu + bias[n%768], dest from lp2w)
__global__ __launch_bounds__(256) void k_bgemm(
    const u16* __restrict__ A, const u16* __restrict__ B,
    const float* __restrict__ bias,
    float* __restrict__ Cf, u16* __restrict__ Cb,
    int M, int N, int K, int lda, int ldb, int ldcf, int ldcb,
    int flags, int lp2w) {
  __shared__ u16 As[128 * 32];
  __shared__ u16 Bs[128 * 32];
  const int tid = threadIdx.x;
  const int m0 = blockIdx.y << 7, n0 = blockIdx.x << 7;
  const int wv = tid >> 6, ln = tid & 63;
  const int wm = (wv >> 1) << 6, wn = (wv & 1) << 6;
  const int fr = ln & 15, fq = ln >> 4;
  floatx4 acc[4][4];
#pragma unroll
  for (int i = 0; i < 4; i++)
#pragma unroll
    for (int j = 0; j < 4; j++) acc[i][j] = (floatx4){0.f, 0.f, 0.f, 0.f};

  const int c0 = tid, c1 = tid + 256;
  const u16* Ag0 = A + (size_t)min(m0 + (c0 >> 2), M - 1) * lda + ((c0 & 3) << 3);
  const u16* Ag1 = A + (size_t)min(m0 + (c1 >> 2), M - 1) * lda + ((c1 & 3) << 3);
  const u16* Bg0 = B + (size_t)min(n0 + (c0 >> 2), N - 1) * ldb + ((c0 & 3) << 3);
  const u16* Bg1 = B + (size_t)min(n0 + (c1 >> 2), N - 1) * ldb + ((c1 & 3) << 3);
  u16* Al0 = As + c0 * 8;
  u16* Al1 = As + c1 * 8;
  u16* Bl0 = Bs + c0 * 8;
  u16* Bl1 = Bs + c1 * 8;

  for (int k0 = 0; k0 < K; k0 += 32) {
    gl_lds16(Ag0, Al0);
    gl_lds16(Ag1, Al1);
    gl_lds16(Bg0, Bl0);
    gl_lds16(Bg1, Bl1);
    Ag0 += 32; Ag1 += 32; Bg0 += 32; Bg1 += 32;
    __syncthreads();
    bf16x8 af[4], bb[4];
#pragma unroll
    for (int mi = 0; mi < 4; mi++)
      af[mi] = *(const bf16x8*)(As + ((wm + (mi << 4) + fr) << 5) + (fq << 3));
#pragma unroll
    for (int ni = 0; ni < 4; ni++)
      bb[ni] = *(const bf16x8*)(Bs + ((wn + (ni << 4) + fr) << 5) + (fq << 3));
#pragma unroll
    for (int mi = 0; mi < 4; mi++)
#pragma unroll
      for (int ni = 0; ni < 4; ni++)
        acc[mi][ni] = __builtin_amdgcn_mfma_f32_16x16x32_bf16(af[mi], bb[ni], acc[mi][ni], 0, 0, 0);
    __syncthreads();
  }

  // C/D layout: col = lane&15 (n), row = (lane>>4)*4 + reg (m)  [m89-verified]
#pragma unroll
  for (int mi = 0; mi < 4; mi++) {
#pragma unroll
    for (int ni = 0; ni < 4; ni++) {
#pragma unroll
      for (int r = 0; r < 4; r++) {
        int m = m0 + wm + (mi << 4) + (fq << 2) + r;
        int n = n0 + wn + (ni << 4) + fr;
        if (m >= M || n >= N) continue;
        float v = acc[mi][ni][r];
        if (flags & 2) {
          int o = n % 768, dx = n / 768;
          v = geluf(v + bias[o]);
          int W = 1 << lp2w;
          int y = m >> lp2w, x = m & (W - 1);
          size_t dp = ((size_t)y << (lp2w + 2)) + ((size_t)x << 1) +
                      ((size_t)(dx >> 1) << (lp2w + 1)) + (dx & 1);
          Cb[dp * 768 + o] = f2b(v);
        } else {
          if (bias) v += bias[n];
          if (flags & 1) v = geluf(v);
          if (Cf) Cf[(size_t)m * ldcf + n] = v;
          if (Cb) Cb[(size_t)m * ldcb + n] = f2b(v);
        }
      }
    }
  }
}

// ---------------- row LayerNorm over 768, bf16 out ----------------
template <typename T>
__global__ __launch_bounds__(256) void k_ln(const T* __restrict__ X,
                                            const float* __restrict__ w,
                                            const float* __restrict__ b,
                                            u16* __restrict__ out) {
  const int row = blockIdx.x, tid = threadIdx.x;
  const T* xr = X + (size_t)row * CH;
  float v0 = ldv(xr + tid), v1 = ldv(xr + tid + 256), v2 = ldv(xr + tid + 512);
  __shared__ float red[256];
  red[tid] = v0 + v1 + v2;
  __syncthreads();
  for (int s = 128; s > 0; s >>= 1) { if (tid < s) red[tid] += red[tid + s]; __syncthreads(); }
  float m = red[0] * (1.0f / CH);
  __syncthreads();
  float d0 = v0 - m, d1 = v1 - m, d2 = v2 - m;
  red[tid] = d0 * d0 + d1 * d1 + d2 * d2;
  __syncthreads();
  for (int s = 128; s > 0; s >>= 1) { if (tid < s) red[tid] += red[tid + s]; __syncthreads(); }
  float rstd = rsqrtf(red[0] * (1.0f / CH) + 1e-6f);
  u16* orow = out + (size_t)row * CH;
  orow[tid]       = f2b(d0 * rstd * w[tid]       + b[tid]);
  orow[tid + 256] = f2b(d1 * rstd * w[tid + 256] + b[tid + 256]);
  orow[tid + 512] = f2b(d2 * rstd * w[tid + 512] + b[tid + 512]);
}

// ---------------- fused attention (bf16 in/out, fp32 math) ----------------
__global__ __launch_bounds__(256) void k_attn(const u16* __restrict__ qkv,
                                              u16* __restrict__ out,
                                              const unsigned char* __restrict__ qm,
                                              int Ntok) {
  const int b = blockIdx.z, h = blockIdx.y, q0 = blockIdx.x * QT;
  const int tid = threadIdx.x;
  __shared__ float qs[QT][DHEAD];
  __shared__ float ks[64][DHEAD + 4];
  __shared__ float srow[QT][1152];
  __shared__ float red[256];
  __shared__ float inv[QT];

  for (int idx = tid; idx < QT * DHEAD; idx += 256) {
    int r = idx >> 6, d = idx & 63;
    float v = 0.f;
    if (q0 + r < Ntok) v = b2f(qkv[(size_t)(b * Ntok + q0 + r) * (3 * CH) + h * DHEAD + d]) * 0.125f;
    qs[r][d] = v;
  }
  __syncthreads();

  const int kj = tid >> 2, kd0 = (tid & 3) << 4;
  const int jj = tid & 63, rg = tid >> 6;
  for (int nb = 0; nb < Ntok; nb += 64) {
    const int nk = min(64, Ntok - nb);
    if (kj < nk) {
      const u16* kp = qkv + (size_t)(b * Ntok + nb + kj) * (3 * CH) + CH + h * DHEAD + kd0;
#pragma unroll
      for (int i = 0; i < 16; i++) ks[kj][kd0 + i] = b2f(kp[i]);
    }
    __syncthreads();
    if (jj < nk) {
      float a0 = 0.f, a1 = 0.f;
#pragma unroll
      for (int d = 0; d < DHEAD; d += 4) {
        float4 kv = *(const float4*)&ks[jj][d];
        float4 qa = *(const float4*)&qs[rg][d];
        float4 qb = *(const float4*)&qs[rg + 4][d];
        a0 = fmaf(kv.x, qa.x, a0); a0 = fmaf(kv.y, qa.y, a0);
        a0 = fmaf(kv.z, qa.z, a0); a0 = fmaf(kv.w, qa.w, a0);
        a1 = fmaf(kv.x, qb.x, a1); a1 = fmaf(kv.y, qb.y, a1);
        a1 = fmaf(kv.z, qb.z, a1); a1 = fmaf(kv.w, qb.w, a1);
      }
      int n = nb + jj;
      if (qm && n >= NQUERY + NPREFIX) {
        int r0 = q0 + rg, r1 = q0 + rg + 4;
        int pk = n - (NQUERY + NPREFIX);
        if (r0 < NQUERY && !qm[(b * NQUERY + r0) * NPATCHES + pk]) a0 = -1e30f;
        if (r1 < NQUERY && !qm[(b * NQUERY + r1) * NPATCHES + pk]) a1 = -1e30f;
      }
      srow[rg][n] = a0;
      srow[rg + 4][n] = a1;
    }
    __syncthreads();
  }

  for (int r = 0; r < QT; r++) {
    float mx = -1e30f;
    for (int n = tid; n < Ntok; n += 256) mx = fmaxf(mx, srow[r][n]);
    red[tid] = mx; __syncthreads();
    for (int s = 128; s > 0; s >>= 1) { if (tid < s) red[tid] = fmaxf(red[tid], red[tid + s]); __syncthreads(); }
    mx = red[0]; __syncthreads();
    float sum = 0.f;
    for (int n = tid; n < Ntok; n += 256) {
      float e = __expf(srow[r][n] - mx);
      srow[r][n] = e; sum += e;
    }
    red[tid] = sum; __syncthreads();
    for (int s = 128; s > 0; s >>= 1) { if (tid < s) red[tid] += red[tid + s]; __syncthreads(); }
    if (tid == 0) inv[r] = 1.0f / red[0];
    __syncthreads();
  }

  const int d = tid & 63, qr = tid >> 6;
  float oacc[QT];
#pragma unroll
  for (int r = 0; r < QT; r++) oacc[r] = 0.f;
  for (int n = qr; n < Ntok; n += 4) {
    float vv = b2f(qkv[(size_t)(b * Ntok + n) * (3 * CH) + 2 * CH + h * DHEAD + d]);
#pragma unroll
    for (int r = 0; r < QT; r++) oacc[r] = fmaf(srow[r][n], vv, oacc[r]);
  }
  for (int r = 0; r < QT; r++) {
    red[tid] = oacc[r]; __syncthreads();
    if (qr == 0 && q0 + r < Ntok) {
      float t = (red[d] + red[64 + d]) + (red[128 + d] + red[192 + d]);
      out[(size_t)(b * Ntok + q0 + r) * CH + h * DHEAD + d] = f2b(t * inv[r]);
    }
    __syncthreads();
  }
}

// ---------------- misc elementwise ----------------
__global__ void k_patchify(const float* __restrict__ x, const float* __restrict__ mean,
                           const float* __restrict__ stdv, u16* __restrict__ xp) {
  int idx = blockIdx.x * 256 + threadIdx.x;
  if (idx >= BSZ * NPATCHES * CH) return;
  int f = idx % CH;
  int p = (idx / CH) % NPATCHES;
  int b = idx / (CH * NPATCHES);
  int c = f >> 8;
  int py = (f >> 4) & 15;
  int px = f & 15;
  int gy = p >> 5, gx = p & 31;
  float v = x[((size_t)(b * 3 + c) * IMGSZ + gy * 16 + py) * IMGSZ + gx * 16 + px];
  xp[idx] = f2b((v * (1.0f / 255.0f) - mean[c]) / stdv[c]);
}

__global__ void k_assemble(const float* __restrict__ xpe, const float* __restrict__ prefix,
                           const float* __restrict__ pos, float* __restrict__ X) {
  int idx = blockIdx.x * 256 + threadIdx.x;
  if (idx >= BSZ * NTOK1 * CH) return;
  int c = idx % CH;
  int n = (idx / CH) % NTOK1;
  int b = idx / (CH * NTOK1);
  float v;
  if (n < NPREFIX) v = prefix[n * CH + c];
  else v = xpe[((size_t)b * NPATCHES + n - NPREFIX) * CH + c] + pos[(size_t)(n - NPREFIX) * CH + c];
  X[idx] = v;
}

__global__ void k_concat(const float* __restrict__ Xin, const float* __restrict__ qe,
                         float* __restrict__ Xout) {
  int idx = blockIdx.x * 256 + threadIdx.x;
  if (idx >= BSZ * NTOK2 * CH) return;
  int c = idx % CH;
  int n = (idx / CH) % NTOK2;
  int b = idx / (CH * NTOK2);
  float v;
  if (n < NQUERY) v = qe[n * CH + c];
  else v = Xin[((size_t)b * NTOK1 + n - NQUERY) * CH + c];
  Xout[idx] = v;
}

__global__ void k_residual(float* __restrict__ X, const float* __restrict__ Y,
                           const float* __restrict__ ls, int total) {
  int idx = blockIdx.x * 256 + threadIdx.x;
  if (idx >= total) return;
  X[idx] += ls[idx % CH] * Y[idx];
}

// depthwise 3x3, pixel-major (HW, C) layout, bf16 in/out
__global__ void k_dwconv(const u16* __restrict__ in, const float* __restrict__ w9,
                         u16* __restrict__ out, int H, int W) {
  int idx = blockIdx.x * 256 + threadIdx.x;
  if (idx >= CH * H * W) return;
  int c = idx % CH;
  int pix = idx / CH;
  int x = pix % W, y = pix / W;
  const float* wp = w9 + c * 9;
  float s = 0.f;
#pragma unroll
  for (int ky = 0; ky < 3; ky++) {
    int yy = y + ky - 1;
    if (yy < 0 || yy >= H) continue;
#pragma unroll
    for (int kx = 0; kx < 3; kx++) {
      int xx = x + kx - 1;
      if (xx < 0 || xx >= W) continue;
      s = fmaf(wp[ky * 3 + kx], b2f(in[((size_t)yy * W + xx) * CH + c]), s);
    }
  }
  out[idx] = f2b(s);
}

// repack upt_w (s, c, o, d, x) -> WPb[s][dx*768+o][c], bf16
__global__ __launch_bounds__(256) void k_repack(const float* __restrict__ upt,
                                                u16* __restrict__ WPb) {
  __shared__ float t[4][32][33];
  int o0 = blockIdx.x * 32, c0 = blockIdx.y * 32, s = blockIdx.z;
  int tid = threadIdx.x;
  for (int idx = tid; idx < 32 * 128; idx += 256) {
    int cc = idx >> 7;
    int rest = idx & 127;
    int oo = rest >> 2, dx = rest & 3;
    t[dx][oo][cc] = upt[((size_t)(s * CH + c0 + cc) * CH + o0 + oo) * 4 + dx];
  }
  __syncthreads();
  for (int idx = tid; idx < 4 * 32 * 32; idx += 256) {
    int dx = idx >> 10;
    int oo = (idx >> 5) & 31;
    int cc = idx & 31;
    WPb[((size_t)(s * 4 + dx) * CH + o0 + oo) * CH + c0 + cc] = f2b(t[dx][oo][cc]);
  }
}

// antialiased bilinear 128->32 downsample + threshold>0
__global__ void k_qmask(const float* __restrict__ mlog, unsigned char* __restrict__ qm) {
  int idx = blockIdx.x * 256 + threadIdx.x;
  if (idx >= BSZ * NQUERY * NPATCHES) return;
  int gx = idx & 31;
  int gy = (idx >> 5) & 31;
  int bq = idx >> 10;
  const float* m = mlog + (size_t)bq * 16384;
  float cy = 4.0f * gy + 1.5f, cx = 4.0f * gx + 1.5f;
  int y0 = max(0, 4 * gy - 2), y1 = min(127, 4 * gy + 5);
  int x0 = max(0, 4 * gx - 2), x1 = min(127, 4 * gx + 5);
  float num = 0.f;
  for (int jy = y0; jy <= y1; jy++) {
    float wy = 1.0f - fabsf((float)jy - cy) * 0.25f;
    float rowsum = 0.f;
    for (int jx = x0; jx <= x1; jx++) {
      float wx = 1.0f - fabsf((float)jx - cx) * 0.25f;
      rowsum = fmaf(wx, m[jy * 128 + jx], rowsum);
    }
    num = fmaf(wy, rowsum, num);
  }
  qm[idx] = (num > 0.0f) ? 1 : 0;
}

// ---------------- host orchestration ----------------
extern "C" void kernel_launch(void* const* d_in, const int* in_sizes, int n_in,
                              void* d_out_v, int out_size, void* d_ws, size_t ws_size,
                              hipStream_t stream) {
  (void)in_sizes; (void)n_in; (void)out_size; (void)ws_size;
  const float* x_in    = (const float*)d_in[0];
  const float* pmean   = (const float*)d_in[1];
  const float* pstd    = (const float*)d_in[2];
  const float* patch_w = (const float*)d_in[3];
  const float* patch_b = (const float*)d_in[4];
  const float* pos     = (const float*)d_in[5];
  const float* prefix  = (const float*)d_in[6];
  const float* qkv_w   = (const float*)d_in[7];
  const float* qkv_b   = (const float*)d_in[8];
  const float* proj_w  = (const float*)d_in[9];
  const float* proj_b  = (const float*)d_in[10];
  const float* ln1w    = (const float*)d_in[11];
  const float* ln1b    = (const float*)d_in[12];
  const float* ln2w    = (const float*)d_in[13];
  const float* ln2b    = (const float*)d_in[14];
  const float* ls1     = (const float*)d_in[15];
  const float* ls2     = (const float*)d_in[16];
  const float* fc1w    = (const float*)d_in[17];
  const float* fc1b    = (const float*)d_in[18];
  const float* fc2w    = (const float*)d_in[19];
  const float* fc2b    = (const float*)d_in[20];
  const float* normw   = (const float*)d_in[21];
  const float* normb   = (const float*)d_in[22];
  const float* qemb    = (const float*)d_in[23];
  const float* clsw    = (const float*)d_in[24];
  const float* clsb    = (const float*)d_in[25];
  const float* mh1w    = (const float*)d_in[26];
  const float* mh1b    = (const float*)d_in[27];
  const float* mh2w    = (const float*)d_in[28];
  const float* mh2b    = (const float*)d_in[29];
  const float* mh3w    = (const float*)d_in[30];
  const float* mh3b    = (const float*)d_in[31];
  const float* uptw    = (const float*)d_in[32];
  const float* uptb    = (const float*)d_in[33];
  const float* updww   = (const float*)d_in[34];
  const float* uplnw   = (const float*)d_in[35];
  const float* uplnb   = (const float*)d_in[36];

  float* out = (float*)d_out_v;
  float* out_mask = out;                                   // (5,2,100,128,128)
  float* out_cls = out + (size_t)5 * BSZ * NQUERY * 16384; // (5,2,100,151)

  char* base = (char*)d_ws;
  size_t off = 0;
  auto allocB = [&](size_t bytes) {
    void* p = base + off;
    off += (bytes + 63) & ~(size_t)63;
    return p;
  };
  // fp32
  float* Xa = (float*)allocB((size_t)BSZ * NTOK2 * CH * 4);
  float* Xb = (float*)allocB((size_t)BSZ * NTOK2 * CH * 4);
  float* Hf = (float*)allocB((size_t)BSZ * NTOK2 * CH * 4);   // proj/fc2/XPE staging
  // bf16
  u16* Wq  = (u16*)allocB((size_t)3 * CH * CH * 2);
  u16* Wp  = (u16*)allocB((size_t)CH * CH * 2);
  u16* Wf1 = (u16*)allocB((size_t)4 * CH * CH * 2);
  u16* Wf2 = (u16*)allocB((size_t)CH * 4 * CH * 2);
  u16* Wpa = (u16*)allocB((size_t)CH * CH * 2);
  u16* Wcl = (u16*)allocB((size_t)NCLASS * CH * 2);
  u16* Wm1 = (u16*)allocB((size_t)CH * CH * 2);
  u16* Wm2 = (u16*)allocB((size_t)CH * CH * 2);
  u16* Wm3 = (u16*)allocB((size_t)CH * CH * 2);
  u16* WPb = (u16*)allocB((size_t)2 * 4 * CH * CH * 2);
  u16* LNb = (u16*)allocB((size_t)BSZ * NTOK2 * CH * 2);
  u16* AOb = (u16*)allocB((size_t)BSZ * NTOK2 * CH * 2);
  u16* XPb = (u16*)allocB((size_t)BSZ * NPATCHES * CH * 2);
  u16* HQa = (u16*)allocB((size_t)BSZ * NQUERY * CH * 2);
  u16* HQb = (u16*)allocB((size_t)BSZ * NQUERY * CH * 2);
  u16* HQc = (u16*)allocB((size_t)BSZ * NQUERY * CH * 2);
  u16* Sb  = (u16*)allocB((size_t)2 * 16384 * CH * 2);        // shared big region
  unsigned char* QM = (unsigned char*)allocB((size_t)BSZ * NQUERY * NPATCHES);

  u16* QKVb = Sb;                        // rows x 2304 (in-layer)
  u16* M1b  = Sb;                        // rows x 3072 (in-layer)
  u16* s0g  = Sb;                        // 4096  x 768
  u16* s0d  = Sb + (size_t)4096 * CH;    // 4096  x 768
  u16* s0l  = Sb + (size_t)8192 * CH;    // 4096  x 768
  u16* s1g  = Sb + (size_t)16384 * CH;   // 16384 x 768
  u16* s1d  = Sb;                        // 16384 x 768
  u16* s1l  = Sb + (size_t)16384 * CH;   // 16384 x 768

  auto bgemm = [&](const u16* A, const u16* B, const float* bias, float* Cf, u16* Cb,
                   int M, int N, int K, int lda, int ldb, int ldcf, int ldcb,
                   int flags, int lp2w) {
    dim3 g((N + 127) / 128, (M + 127) / 128);
    k_bgemm<<<g, 256, 0, stream>>>(A, B, bias, Cf, Cb, M, N, K, lda, ldb, ldcf, ldcb, flags, lp2w);
  };
  auto cvt = [&](const float* s, u16* d, int n) {
    k_cvt<<<(n / 4 + 255) / 256, 256, 0, stream>>>(s, d, n);
  };
  auto ew = [&](long tot) { return dim3((unsigned)((tot + 255) / 256)); };

  // ---- one-time weight conversions ----
  cvt(patch_w, Wpa, CH * CH);
  cvt(clsw, Wcl, NCLASS * CH);
  cvt(mh1w, Wm1, CH * CH);
  cvt(mh2w, Wm2, CH * CH);
  cvt(mh3w, Wm3, CH * CH);
  k_repack<<<dim3(24, 24, 2), 256, 0, stream>>>(uptw, WPb);

  // ---- patch embedding ----
  k_patchify<<<ew((long)BSZ * NPATCHES * CH), 256, 0, stream>>>(x_in, pmean, pstd, XPb);
  bgemm(XPb, Wpa, patch_b, Hf, nullptr, BSZ * NPATCHES, CH, CH, CH, CH, CH, 0, 0, 0);
  k_assemble<<<ew((long)BSZ * NTOK1 * CH), 256, 0, stream>>>(Hf, prefix, pos, Xa);

  float* X = Xa;
  float* Xalt = Xb;

  auto predict = [&](float* Xcur, int pred, bool build_mask) {
    k_ln<float><<<dim3(BSZ * NTOK2), 256, 0, stream>>>(Xcur, normw, normb, LNb);
    for (int b = 0; b < BSZ; b++) {
      const u16* q = LNb + (size_t)b * NTOK2 * CH;
      bgemm(q, Wcl, clsb, out_cls + (size_t)(pred * BSZ + b) * NQUERY * NCLASS, nullptr,
            NQUERY, NCLASS, CH, CH, CH, NCLASS, 0, 0, 0);
      bgemm(q, Wm1, mh1b, nullptr, HQa + (size_t)b * NQUERY * CH,
            NQUERY, CH, CH, CH, CH, 0, CH, 1, 0);
      bgemm(HQa + (size_t)b * NQUERY * CH, Wm2, mh2b, nullptr, HQb + (size_t)b * NQUERY * CH,
            NQUERY, CH, CH, CH, CH, 0, CH, 1, 0);
      bgemm(HQb + (size_t)b * NQUERY * CH, Wm3, mh3b, nullptr, HQc + (size_t)b * NQUERY * CH,
            NQUERY, CH, CH, CH, CH, 0, CH, 0, 0);
    }
    for (int b = 0; b < BSZ; b++) {
      // stage 0: patch tokens (1024,768) -> (64x64,768)
      bgemm(LNb + (size_t)(b * NTOK2 + NQUERY + NPREFIX) * CH, WPb, uptb, nullptr, s0g,
            1024, 4 * CH, CH, CH, CH, 0, 0, 2, 5);
      k_dwconv<<<ew((long)CH * 4096), 256, 0, stream>>>(s0g, updww, s0d, 64, 64);
      k_ln<u16><<<dim3(4096), 256, 0, stream>>>(s0d, uplnw, uplnb, s0l);
      // stage 1: (4096,768) -> (128x128,768)
      bgemm(s0l, WPb + (size_t)4 * CH * CH, uptb + CH, nullptr, s1g,
            4096, 4 * CH, CH, CH, CH, 0, 0, 2, 6);
      k_dwconv<<<ew((long)CH * 16384), 256, 0, stream>>>(s1g, updww + CH * 9, s1d, 128, 128);
      k_ln<u16><<<dim3(16384), 256, 0, stream>>>(s1d, uplnw + CH, uplnb + CH, s1l);
      // mask logits: (100,768) x (16384,768)^T
      bgemm(HQc + (size_t)b * NQUERY * CH, s1l, nullptr,
            out_mask + (size_t)(pred * BSZ + b) * NQUERY * 16384, nullptr,
            NQUERY, 16384, CH, CH, CH, 16384, 0, 0, 0);
    }
    if (build_mask) {
      k_qmask<<<ew((long)BSZ * NQUERY * NPATCHES), 256, 0, stream>>>(
          out_mask + (size_t)pred * BSZ * NQUERY * 16384, QM);
    }
  };

  int Ntok = NTOK1;
  for (int i = 0; i < LAYERS; i++) {
    if (i == LAYERS - NBLK) {
      k_concat<<<ew((long)BSZ * NTOK2 * CH), 256, 0, stream>>>(X, qemb, Xalt);
      float* t = X; X = Xalt; Xalt = t;
      Ntok = NTOK2;
    }
    if (i >= LAYERS - NBLK) predict(X, i - (LAYERS - NBLK), true);
    const int rows = BSZ * Ntok;
    // per-layer weight conversion
    cvt(qkv_w + (size_t)i * 3 * CH * CH, Wq, 3 * CH * CH);
    cvt(proj_w + (size_t)i * CH * CH, Wp, CH * CH);
    cvt(fc1w + (size_t)i * 4 * CH * CH, Wf1, 4 * CH * CH);
    cvt(fc2w + (size_t)i * CH * 4 * CH, Wf2, CH * 4 * CH);
    // attention block
    k_ln<float><<<dim3(rows), 256, 0, stream>>>(X, ln1w + i * CH, ln1b + i * CH, LNb);
    bgemm(LNb, Wq, qkv_b + (size_t)i * 3 * CH, nullptr, QKVb,
          rows, 3 * CH, CH, CH, CH, 0, 3 * CH, 0, 0);
    k_attn<<<dim3((Ntok + QT - 1) / QT, 12, BSZ), 256, 0, stream>>>(
        QKVb, AOb, (i >= LAYERS - NBLK) ? QM : (const unsigned char*)nullptr, Ntok);
    bgemm(AOb, Wp, proj_b + (size_t)i * CH, Hf, nullptr,
          rows, CH, CH, CH, CH, CH, 0, 0, 0);
    k_residual<<<ew((long)rows * CH), 256, 0, stream>>>(X, Hf, ls1 + i * CH, rows * CH);
    // MLP block
    k_ln<float><<<dim3(rows), 256, 0, stream>>>(X, ln2w + i * CH, ln2b + i * CH, LNb);
    bgemm(LNb, Wf1, fc1b + (size_t)i * 4 * CH, nullptr, M1b,
          rows, 4 * CH, CH, CH, CH, 0, 4 * CH, 1, 0);
    bgemm(M1b, Wf2, fc2b + (size_t)i * CH, Hf, nullptr,
          rows, CH, 4 * CH, 4 * CH, 4 * CH, CH, 0, 0, 0);
    k_residual<<<ew((long)rows * CH), 256, 0, stream>>>(X, Hf, ls2 + i * CH, rows * CH);
  }
  predict(X, 4, false);
}